// Round 12
// baseline (124.306 us; speedup 1.0000x reference)
//
#include <hip/hip_runtime.h>
#include <math.h>

#define NN 4096
#define DD 512
#define MARGINF 1.0f
#define NCLS 64
#define MAXM 160
#define TRI (MAXM * (MAXM - 1) / 2)   // 12720
#define NBLK 2080                     // 64*65/2 triangular 64-tiles

typedef __attribute__((ext_vector_type(8))) short bf16x8;  // 8 bf16 (4 VGPRs)
typedef __attribute__((ext_vector_type(4))) float f32x4;   // 4 fp32 acc

// ws layout (float indices):
#define WS_SQ   0         // float[4096] ||x_i||^2
#define WS_LOSS 8192      // float[1] sum hinge^2
#define WS_CTR  8193      // uint[1] pair2 completion counter
#define WS_LENP 8194      // float[1] sum over classes mc*(mc-1)
#define WS_RK   8320      // int[4096] rank within class (atomic-free)
#define WS_MEM  12416     // int[64*160] class member lists (rank-indexed)
#define WS_P    32768     // float[4096][128] ns partials: P[i][opp*2+h],
                          //   h = opposing-dim half; each slot written exactly
                          //   once (2 MB, no atomics, no init)
#define WS_XF   557056    // ushort[4096*512] FRAGMENT-MAJOR bf16 X (4 MB)
                          //   Xf[((r16*16 + kb)*64 + (k>>3&3)*16 + (row&15))*8 + (k&7)]
#define WS_PD   1605632   // float[64*TRI] positive-pair distances

__device__ __forceinline__ unsigned short f2bf(float f) {
    unsigned u = __float_as_uint(f);
    u += 0x7fffu + ((u >> 16) & 1u);   // round-to-nearest-even
    return (unsigned short)(u >> 16);
}

// Row norms + fragment-major bf16 conversion + ATOMIC-FREE class ranks.
// rk[i] = #{j<i : tgt[j]==tgt[i]} via LDS scan; mem[c][rk]=i is race-free.
__global__ __launch_bounds__(256) void prep_kernel(const float* __restrict__ X,
                                                   const int* __restrict__ tgt,
                                                   float* __restrict__ ws) {
    __shared__ int tg[NN];   // 16 KB
    const int tid = threadIdx.x;
    for (int j = tid; j < NN; j += 256) tg[j] = tgt[j];

    const int wv = tid >> 6, lane = tid & 63;
    const int row = blockIdx.x * 4 + wv;
    const float4* xr = (const float4*)(X + (size_t)row * DD);
    float4 a = xr[2 * lane], b = xr[2 * lane + 1];   // floats 8*lane..8*lane+7
    float s = a.x * a.x + a.y * a.y + a.z * a.z + a.w * a.w
            + b.x * b.x + b.y * b.y + b.z * b.z + b.w * b.w;
#pragma unroll
    for (int off = 32; off; off >>= 1) s += __shfl_down(s, off, 64);

    ushort4 pa = {f2bf(a.x), f2bf(a.y), f2bf(a.z), f2bf(a.w)};
    ushort4 pb = {f2bf(b.x), f2bf(b.y), f2bf(b.z), f2bf(b.w)};
    const int r16 = row >> 4, m = row & 15;
    const int kb = lane >> 2, q = lane & 3;
    ushort4* dst = (ushort4*)((unsigned short*)(ws + WS_XF)
                              + ((size_t)(r16 * 16 + kb) * 64 + q * 16 + m) * 8);
    dst[0] = pa;
    dst[1] = pb;

    __syncthreads();
    const int myc = tg[row];
    int cnt = 0;
    for (int j = lane; j < row; j += 64) cnt += (tg[j] == myc) ? 1 : 0;
#pragma unroll
    for (int off = 32; off; off >>= 1) cnt += __shfl_down(cnt, off, 64);
    if (lane == 0) {
        ws[WS_SQ + row] = s;
        ((int*)(ws + WS_RK))[row] = cnt;
        if (cnt < MAXM) ((int*)(ws + WS_MEM))[myc * MAXM + cnt] = row;
    }
    if (blockIdx.x == 0 && tid == 0) {
        ws[WS_LOSS] = 0.0f;
        ((unsigned*)ws)[WS_CTR] = 0u;
        ws[WS_LENP] = 0.0f;
    }
}

// Gram via bf16 MFMA, fragment-major coalesced loads, 64x64 tile per block
// (triangular grid), depth-1 prefetch (R9 structure). Epilogue writes ns
// PARTIALS as plain stores -- zero global atomics. Slot [i][opp*2+h]:
// row-side h=wc>>5 (which column half contributed), col-side h=wr>>5
// (which row half) -> every slot written by exactly one wave.
__global__ __launch_bounds__(256, 6) void negsum_kernel(const int* __restrict__ tgt,
                                                        float* __restrict__ ws) {
    const int bidx = blockIdx.x;
    int bj = (int)((sqrtf(8.0f * (float)bidx + 1.0f) - 1.0f) * 0.5f);
    while (bj * (bj + 1) / 2 > bidx) --bj;
    while ((bj + 1) * (bj + 2) / 2 <= bidx) ++bj;
    const int bi = bidx - bj * (bj + 1) / 2;   // bi <= bj
    const int i0 = bi * 64, j0 = bj * 64;

    const int tid = threadIdx.x;
    const int w = tid >> 6, lane = tid & 63;
    const int m_ = lane & 15, q = lane >> 4;
    const int wr = (w & 1) * 32, wc = (w >> 1) * 32;
    const unsigned short* Xf = (const unsigned short*)(ws + WS_XF);

    const int air = (i0 + wr) >> 4;
    const int bjr = (j0 + wc) >> 4;
    const unsigned short* pA = Xf + (size_t)air * 8192 + lane * 8;
    const unsigned short* pB = Xf + (size_t)bjr * 8192 + lane * 8;

    f32x4 acc[2][2] = {};
    bf16x8 af[2], bfr[2], nA[2], nB[2];
#pragma unroll
    for (int u = 0; u < 2; ++u) {
        af[u]  = *(const bf16x8*)(pA + u * 8192);
        bfr[u] = *(const bf16x8*)(pB + u * 8192);
    }
#pragma unroll
    for (int it = 0; it < 16; ++it) {
        if (it < 15) {
#pragma unroll
            for (int u = 0; u < 2; ++u) {
                nA[u] = *(const bf16x8*)(pA + u * 8192 + (it + 1) * 512);
                nB[u] = *(const bf16x8*)(pB + u * 8192 + (it + 1) * 512);
            }
        }
        acc[0][0] = __builtin_amdgcn_mfma_f32_16x16x32_bf16(af[0], bfr[0], acc[0][0], 0, 0, 0);
        acc[0][1] = __builtin_amdgcn_mfma_f32_16x16x32_bf16(af[0], bfr[1], acc[0][1], 0, 0, 0);
        acc[1][0] = __builtin_amdgcn_mfma_f32_16x16x32_bf16(af[1], bfr[0], acc[1][0], 0, 0, 0);
        acc[1][1] = __builtin_amdgcn_mfma_f32_16x16x32_bf16(af[1], bfr[1], acc[1][1], 0, 0, 0);
#pragma unroll
        for (int u = 0; u < 2; ++u) { af[u] = nA[u]; bfr[u] = nB[u]; }
    }

    // epilogue: C/D map col=lane&15, row=(lane>>4)*4+reg
    const float* sq = ws + WS_SQ;
    float* P = ws + WS_P;
    const int* rk = (const int*)(ws + WS_RK);
    float* posd = ws + WS_PD;
    const int hrow = wc >> 5;   // which column-half this wave's row-partial covers
    const int hcol = wr >> 5;   // which row-half this wave's col-partial covers
    float sjv[2]; int tjv[2], jv[2];
#pragma unroll
    for (int v = 0; v < 2; ++v) {
        int j = j0 + wc + v * 16 + m_;
        jv[v] = j;
        sjv[v] = sq[j];
        tjv[v] = tgt[j];
    }
    float colp[2] = {0.0f, 0.0f};
#pragma unroll
    for (int u = 0; u < 2; ++u) {
#pragma unroll
        for (int r = 0; r < 4; ++r) {
            const int i = i0 + wr + u * 16 + q * 4 + r;
            const float si = sq[i];
            const int ti = tgt[i];
            float rp = 0.0f;
#pragma unroll
            for (int v = 0; v < 2; ++v) {
                float d2 = si + sjv[v] - 2.0f * acc[u][v][r];
                float dist = d2 > 0.0f ? sqrtf(d2) : 0.0f;
                if (tjv[v] != ti) {
                    float e = __expf(MARGINF - dist);
                    rp += e;
                    colp[v] += e;
                } else if (i < jv[v]) {
                    int ra = rk[i], rb = rk[jv[v]];
                    if (ra < MAXM && rb < MAXM) {
                        int hi = ra > rb ? ra : rb;
                        int lo = ra > rb ? rb : ra;
                        posd[ti * TRI + hi * (hi - 1) / 2 + lo] = dist;
                    }
                }
            }
            rp += __shfl_xor(rp, 1, 64);
            rp += __shfl_xor(rp, 2, 64);
            rp += __shfl_xor(rp, 4, 64);
            rp += __shfl_xor(rp, 8, 64);
            if (m_ == 0) P[(size_t)i * 128 + bj * 2 + hrow] = rp;   // unique slot
        }
    }
    if (bi != bj) {   // symmetric contribution: G[j][i] == G[i][j]
#pragma unroll
        for (int v = 0; v < 2; ++v) {
            float cp = colp[v];
            cp += __shfl_xor(cp, 16, 64);
            cp += __shfl_xor(cp, 32, 64);
            if (q == 0) P[(size_t)jv[v] * 128 + bi * 2 + hcol] = cp;  // unique slot
        }
    }
}

// Positive pairs: reconstruct ns for this class's members from P partials
// (128 coalesced floats + shuffle reduce per member), then hinge^2.
__global__ __launch_bounds__(256) void pair2_kernel(const int* __restrict__ tgt,
                                                    float* __restrict__ ws,
                                                    float* __restrict__ out) {
    __shared__ float nsm[MAXM];
    __shared__ float wsum[4];
    __shared__ int csum[4];
    __shared__ bool last;
    const int c = blockIdx.x;
    const int tid = threadIdx.x;
    const int wv = tid >> 6, lane = tid & 63;

    int ccount = 0;
    for (int j = tid; j < NN; j += 256) ccount += (tgt[j] == c) ? 1 : 0;
#pragma unroll
    for (int off = 32; off; off >>= 1) ccount += __shfl_down(ccount, off, 64);
    if (lane == 0) csum[wv] = ccount;
    __syncthreads();
    int mc = csum[0] + csum[1] + csum[2] + csum[3];
    if (mc > MAXM) mc = MAXM;
    const int P_ = mc * (mc - 1) / 2;
    const int* mem = (const int*)(ws + WS_MEM) + c * MAXM;
    const float* Pp = ws + WS_P;

    for (int p = wv; p < mc; p += 4) {       // one wave per member
        const float* row = Pp + (size_t)mem[p] * 128;
        float v = row[lane] + row[lane + 64];
#pragma unroll
        for (int off = 32; off; off >>= 1) v += __shfl_xor(v, off, 64);
        if (lane == 0) nsm[p] = v;
    }
    __syncthreads();

    const float* pd = ws + WS_PD + c * TRI;
    float lsum = 0.0f;
    for (int p = tid; p < P_; p += 256) {
        int b = (int)((1.0f + sqrtf(1.0f + 8.0f * (float)p)) * 0.5f);
        while (b * (b - 1) / 2 > p) --b;
        while ((b + 1) * b / 2 <= p) ++b;
        const int a = p - b * (b - 1) / 2;
        const float dist = pd[b * (b - 1) / 2 + a];
        float J = __logf(nsm[a] + nsm[b]) + dist;
        float h = fmaxf(J, 0.0f);
        lsum += h * h;
    }
#pragma unroll
    for (int off = 32; off; off >>= 1) lsum += __shfl_xor(lsum, off, 64);
    if (lane == 0) wsum[wv] = lsum;
    __syncthreads();
    if (tid == 0) {
        float s = wsum[0] + wsum[1] + wsum[2] + wsum[3];
        if (s != 0.0f) atomicAdd(&ws[WS_LOSS], s);
        atomicAdd(&ws[WS_LENP], (float)(mc * (mc - 1)));
        __threadfence();
        unsigned d = atomicAdd((unsigned*)ws + WS_CTR, 1u);
        last = (d == NCLS - 1);
    }
    __syncthreads();
    if (last && tid == 0) {
        float total = atomicAdd(&ws[WS_LOSS], 0.0f);   // device-scope reads
        float lp = atomicAdd(&ws[WS_LENP], 0.0f);
        out[0] = total / lp;
    }
}

extern "C" void kernel_launch(void* const* d_in, const int* in_sizes, int n_in,
                              void* d_out, int out_size, void* d_ws, size_t ws_size,
                              hipStream_t stream) {
    const float* X  = (const float*)d_in[0];
    const int*  tgt = (const int*)d_in[1];
    float* ws  = (float*)d_ws;
    float* out = (float*)d_out;

    hipLaunchKernelGGL(prep_kernel, dim3(NN / 4), dim3(256), 0, stream, X, tgt, ws);
    hipLaunchKernelGGL(negsum_kernel, dim3(NBLK), dim3(256), 0, stream, tgt, ws);
    hipLaunchKernelGGL(pair2_kernel, dim3(NCLS), dim3(256), 0, stream, tgt, ws, out);
}

// Round 13
// 121.158 us; speedup vs baseline: 1.0260x; 1.0260x over previous
//
#include <hip/hip_runtime.h>
#include <math.h>

#define NN 4096
#define DD 512
#define MARGINF 1.0f
#define NCLS 64
#define MAXM 160
#define TRI (MAXM * (MAXM - 1) / 2)   // 12720
#define NBLK 2080                     // 64*65/2 triangular 64-tiles

typedef __attribute__((ext_vector_type(8))) short bf16x8;  // 8 bf16 (4 VGPRs)
typedef __attribute__((ext_vector_type(4))) float f32x4;   // 4 fp32 acc

// ws layout (float indices):
#define WS_SQ   0         // float[4096] ||x_i||^2
#define WS_LOSS 8192      // float[1] sum hinge^2
#define WS_CTR  8193      // uint[1] pair2 completion counter
#define WS_LENP 8194      // float[1] sum over classes mc*(mc-1)
#define WS_RK   8320      // int[4096] rank within class (atomic-free)
#define WS_MEM  12416     // int[64*160] class member lists (rank-indexed)
#define WS_P    32768     // float[4096][128] ns partials: P[i][opp*2+h],
                          //   h = opposing-dim half; each slot written exactly
                          //   once (2 MB, no atomics, no init)
#define WS_XF   557056    // ushort[4096*512] FRAGMENT-MAJOR bf16 X (4 MB)
                          //   Xf[((r16*16 + kb)*64 + (k>>3&3)*16 + (row&15))*8 + (k&7)]
#define WS_PD   1605632   // float[64*TRI] positive-pair distances

__device__ __forceinline__ unsigned short f2bf(float f) {
    unsigned u = __float_as_uint(f);
    u += 0x7fffu + ((u >> 16) & 1u);   // round-to-nearest-even
    return (unsigned short)(u >> 16);
}

// Row norms + fragment-major bf16 conversion + ATOMIC-FREE class ranks.
// rk[i] = #{j<i : tgt[j]==tgt[i]} via LDS scan; mem[c][rk]=i is race-free.
__global__ __launch_bounds__(256) void prep_kernel(const float* __restrict__ X,
                                                   const int* __restrict__ tgt,
                                                   float* __restrict__ ws) {
    __shared__ int tg[NN];   // 16 KB
    const int tid = threadIdx.x;
    for (int j = tid; j < NN; j += 256) tg[j] = tgt[j];

    const int wv = tid >> 6, lane = tid & 63;
    const int row = blockIdx.x * 4 + wv;
    const float4* xr = (const float4*)(X + (size_t)row * DD);
    float4 a = xr[2 * lane], b = xr[2 * lane + 1];   // floats 8*lane..8*lane+7
    float s = a.x * a.x + a.y * a.y + a.z * a.z + a.w * a.w
            + b.x * b.x + b.y * b.y + b.z * b.z + b.w * b.w;
#pragma unroll
    for (int off = 32; off; off >>= 1) s += __shfl_down(s, off, 64);

    ushort4 pa = {f2bf(a.x), f2bf(a.y), f2bf(a.z), f2bf(a.w)};
    ushort4 pb = {f2bf(b.x), f2bf(b.y), f2bf(b.z), f2bf(b.w)};
    const int r16 = row >> 4, m = row & 15;
    const int kb = lane >> 2, q = lane & 3;
    ushort4* dst = (ushort4*)((unsigned short*)(ws + WS_XF)
                              + ((size_t)(r16 * 16 + kb) * 64 + q * 16 + m) * 8);
    dst[0] = pa;
    dst[1] = pb;

    __syncthreads();
    const int myc = tg[row];
    int cnt = 0;
    for (int j = lane; j < row; j += 64) cnt += (tg[j] == myc) ? 1 : 0;
#pragma unroll
    for (int off = 32; off; off >>= 1) cnt += __shfl_down(cnt, off, 64);
    if (lane == 0) {
        ws[WS_SQ + row] = s;
        ((int*)(ws + WS_RK))[row] = cnt;
        if (cnt < MAXM) ((int*)(ws + WS_MEM))[myc * MAXM + cnt] = row;
    }
    if (blockIdx.x == 0 && tid == 0) {
        ws[WS_LOSS] = 0.0f;
        ((unsigned*)ws)[WS_CTR] = 0u;
        ws[WS_LENP] = 0.0f;
    }
}

// Gram via bf16 MFMA, fragment-major coalesced loads, 64x64 tile per block
// (triangular grid). CHUNK-4 REGISTER DOUBLE BUFFER: 16 fragments (4 K-iters)
// preloaded; per chunk all 16 next-chunk loads issue back-to-back (16
// outstanding global_load_dwordx4) before 16 MFMAs consume the current
// chunk. 2x64 VGPR buffers force the compiler to keep loads in flight
// (R10/R12's depth-1/2 collapsed to VGPR_Count=44 = serialized chain).
// Epilogue: atomic-free P partials (R12 scheme).
__global__ __launch_bounds__(256, 3) void negsum_kernel(const int* __restrict__ tgt,
                                                        float* __restrict__ ws) {
    const int bidx = blockIdx.x;
    int bj = (int)((sqrtf(8.0f * (float)bidx + 1.0f) - 1.0f) * 0.5f);
    while (bj * (bj + 1) / 2 > bidx) --bj;
    while ((bj + 1) * (bj + 2) / 2 <= bidx) ++bj;
    const int bi = bidx - bj * (bj + 1) / 2;   // bi <= bj
    const int i0 = bi * 64, j0 = bj * 64;

    const int tid = threadIdx.x;
    const int w = tid >> 6, lane = tid & 63;
    const int m_ = lane & 15, q = lane >> 4;
    const int wr = (w & 1) * 32, wc = (w >> 1) * 32;
    const unsigned short* Xf = (const unsigned short*)(ws + WS_XF);

    const int air = (i0 + wr) >> 4;
    const int bjr = (j0 + wc) >> 4;
    const unsigned short* pA = Xf + (size_t)air * 8192 + lane * 8;
    const unsigned short* pB = Xf + (size_t)bjr * 8192 + lane * 8;

    f32x4 acc[2][2] = {};
    bf16x8 cur[4][4], nxt[4][4];   // [iter-in-chunk][A0,A1,B0,B1]
#pragma unroll
    for (int s = 0; s < 4; ++s) {
        cur[s][0] = *(const bf16x8*)(pA + s * 512);
        cur[s][1] = *(const bf16x8*)(pA + 8192 + s * 512);
        cur[s][2] = *(const bf16x8*)(pB + s * 512);
        cur[s][3] = *(const bf16x8*)(pB + 8192 + s * 512);
    }
#pragma unroll
    for (int ch = 0; ch < 4; ++ch) {
        if (ch < 3) {
#pragma unroll
            for (int s = 0; s < 4; ++s) {
                const int it = (ch + 1) * 4 + s;
                nxt[s][0] = *(const bf16x8*)(pA + it * 512);
                nxt[s][1] = *(const bf16x8*)(pA + 8192 + it * 512);
                nxt[s][2] = *(const bf16x8*)(pB + it * 512);
                nxt[s][3] = *(const bf16x8*)(pB + 8192 + it * 512);
            }
        }
#pragma unroll
        for (int s = 0; s < 4; ++s) {
            acc[0][0] = __builtin_amdgcn_mfma_f32_16x16x32_bf16(cur[s][0], cur[s][2], acc[0][0], 0, 0, 0);
            acc[0][1] = __builtin_amdgcn_mfma_f32_16x16x32_bf16(cur[s][0], cur[s][3], acc[0][1], 0, 0, 0);
            acc[1][0] = __builtin_amdgcn_mfma_f32_16x16x32_bf16(cur[s][1], cur[s][2], acc[1][0], 0, 0, 0);
            acc[1][1] = __builtin_amdgcn_mfma_f32_16x16x32_bf16(cur[s][1], cur[s][3], acc[1][1], 0, 0, 0);
        }
#pragma unroll
        for (int s = 0; s < 4; ++s)
#pragma unroll
            for (int f = 0; f < 4; ++f)
                cur[s][f] = nxt[s][f];
    }

    // epilogue: C/D map col=lane&15, row=(lane>>4)*4+reg
    const float* sq = ws + WS_SQ;
    float* P = ws + WS_P;
    const int* rk = (const int*)(ws + WS_RK);
    float* posd = ws + WS_PD;
    const int hrow = wc >> 5;   // which column-half this wave's row-partial covers
    const int hcol = wr >> 5;   // which row-half this wave's col-partial covers
    float sjv[2]; int tjv[2], jv[2];
#pragma unroll
    for (int v = 0; v < 2; ++v) {
        int j = j0 + wc + v * 16 + m_;
        jv[v] = j;
        sjv[v] = sq[j];
        tjv[v] = tgt[j];
    }
    float colp[2] = {0.0f, 0.0f};
#pragma unroll
    for (int u = 0; u < 2; ++u) {
#pragma unroll
        for (int r = 0; r < 4; ++r) {
            const int i = i0 + wr + u * 16 + q * 4 + r;
            const float si = sq[i];
            const int ti = tgt[i];
            float rp = 0.0f;
#pragma unroll
            for (int v = 0; v < 2; ++v) {
                float d2 = si + sjv[v] - 2.0f * acc[u][v][r];
                float dist = d2 > 0.0f ? sqrtf(d2) : 0.0f;
                if (tjv[v] != ti) {
                    float e = __expf(MARGINF - dist);
                    rp += e;
                    colp[v] += e;
                } else if (i < jv[v]) {
                    int ra = rk[i], rb = rk[jv[v]];
                    if (ra < MAXM && rb < MAXM) {
                        int hi = ra > rb ? ra : rb;
                        int lo = ra > rb ? rb : ra;
                        posd[ti * TRI + hi * (hi - 1) / 2 + lo] = dist;
                    }
                }
            }
            rp += __shfl_xor(rp, 1, 64);
            rp += __shfl_xor(rp, 2, 64);
            rp += __shfl_xor(rp, 4, 64);
            rp += __shfl_xor(rp, 8, 64);
            if (m_ == 0) P[(size_t)i * 128 + bj * 2 + hrow] = rp;   // unique slot
        }
    }
    if (bi != bj) {   // symmetric contribution: G[j][i] == G[i][j]
#pragma unroll
        for (int v = 0; v < 2; ++v) {
            float cp = colp[v];
            cp += __shfl_xor(cp, 16, 64);
            cp += __shfl_xor(cp, 32, 64);
            if (q == 0) P[(size_t)jv[v] * 128 + bi * 2 + hcol] = cp;  // unique slot
        }
    }
}

// Positive pairs: reconstruct ns for this class's members from P partials
// (128 coalesced floats + shuffle reduce per member), then hinge^2.
__global__ __launch_bounds__(256) void pair2_kernel(const int* __restrict__ tgt,
                                                    float* __restrict__ ws,
                                                    float* __restrict__ out) {
    __shared__ float nsm[MAXM];
    __shared__ float wsum[4];
    __shared__ int csum[4];
    __shared__ bool last;
    const int c = blockIdx.x;
    const int tid = threadIdx.x;
    const int wv = tid >> 6, lane = tid & 63;

    int ccount = 0;
    for (int j = tid; j < NN; j += 256) ccount += (tgt[j] == c) ? 1 : 0;
#pragma unroll
    for (int off = 32; off; off >>= 1) ccount += __shfl_down(ccount, off, 64);
    if (lane == 0) csum[wv] = ccount;
    __syncthreads();
    int mc = csum[0] + csum[1] + csum[2] + csum[3];
    if (mc > MAXM) mc = MAXM;
    const int P_ = mc * (mc - 1) / 2;
    const int* mem = (const int*)(ws + WS_MEM) + c * MAXM;
    const float* Pp = ws + WS_P;

    for (int p = wv; p < mc; p += 4) {       // one wave per member
        const float* row = Pp + (size_t)mem[p] * 128;
        float v = row[lane] + row[lane + 64];
#pragma unroll
        for (int off = 32; off; off >>= 1) v += __shfl_xor(v, off, 64);
        if (lane == 0) nsm[p] = v;
    }
    __syncthreads();

    const float* pd = ws + WS_PD + c * TRI;
    float lsum = 0.0f;
    for (int p = tid; p < P_; p += 256) {
        int b = (int)((1.0f + sqrtf(1.0f + 8.0f * (float)p)) * 0.5f);
        while (b * (b - 1) / 2 > p) --b;
        while ((b + 1) * b / 2 <= p) ++b;
        const int a = p - b * (b - 1) / 2;
        const float dist = pd[b * (b - 1) / 2 + a];
        float J = __logf(nsm[a] + nsm[b]) + dist;
        float h = fmaxf(J, 0.0f);
        lsum += h * h;
    }
#pragma unroll
    for (int off = 32; off; off >>= 1) lsum += __shfl_xor(lsum, off, 64);
    if (lane == 0) wsum[wv] = lsum;
    __syncthreads();
    if (tid == 0) {
        float s = wsum[0] + wsum[1] + wsum[2] + wsum[3];
        if (s != 0.0f) atomicAdd(&ws[WS_LOSS], s);
        atomicAdd(&ws[WS_LENP], (float)(mc * (mc - 1)));
        __threadfence();
        unsigned d = atomicAdd((unsigned*)ws + WS_CTR, 1u);
        last = (d == NCLS - 1);
    }
    __syncthreads();
    if (last && tid == 0) {
        float total = atomicAdd(&ws[WS_LOSS], 0.0f);   // device-scope reads
        float lp = atomicAdd(&ws[WS_LENP], 0.0f);
        out[0] = total / lp;
    }
}

extern "C" void kernel_launch(void* const* d_in, const int* in_sizes, int n_in,
                              void* d_out, int out_size, void* d_ws, size_t ws_size,
                              hipStream_t stream) {
    const float* X  = (const float*)d_in[0];
    const int*  tgt = (const int*)d_in[1];
    float* ws  = (float*)d_ws;
    float* out = (float*)d_out;

    hipLaunchKernelGGL(prep_kernel, dim3(NN / 4), dim3(256), 0, stream, X, tgt, ws);
    hipLaunchKernelGGL(negsum_kernel, dim3(NBLK), dim3(256), 0, stream, tgt, ws);
    hipLaunchKernelGGL(pair2_kernel, dim3(NCLS), dim3(256), 0, stream, tgt, ws, out);
}